// Round 7
// baseline (97.645 us; speedup 1.0000x reference)
//
#include <hip/hip_runtime.h>

// LocalConv: out[b][o][oh][ow] = sum_f patch[p][b][f] * W[p][f][o]
// B=64, C=16, H=W=64, K=3x3, OH=OW=62, OUT_CH=32, FEAT=144, P=3844
// Round 7: barrier-free main loop. 256 thr / 4 waves; wave = 16 batches x
// all 32 outch x TW positions. A-slab in LDS (48KB -> 3 blocks/CU); B
// streamed global->VGPR per wave (no LDS-B, no per-position barriers).
// bf16 via hi-16-bit truncating ushort loads (no cvt VALU anywhere).
// K permuted: f'' = (kh*3+kw)*16 + c ; f = c*9 + g.
#define CIN    16
#define HH     64
#define WW     64
#define OHD    62
#define OWD    62
#define OUTC   32
#define FEATN  144
#define POUT   (OHD*OWD)
#define WBYTES (FEATN*OUTC*4)          // 18432 B per position
#define AR_W   8                       // A slab w-dim (max TW+2)
#define AR_ELEMS (3*AR_W*64*16)        // 24576 ushort = 49152 B

typedef __attribute__((ext_vector_type(8))) short  short8;
typedef __attribute__((ext_vector_type(4))) float  f32x4;
typedef __attribute__((ext_vector_type(2))) float  f32x2;

template<int TW>
__device__ __forceinline__ void conv_body(
    const float* __restrict__ inp, const float* __restrict__ wgt,
    float* __restrict__ out, int oh, int ow0,
    unsigned short* __restrict__ Araw)
{
    const int tid = threadIdx.x;
    constexpr int WTOT = TW + 2;

    const int lane = tid & 63, wid = tid >> 6;     // 4 waves
    const int fr  = lane & 15, fq = lane >> 4, fqh = fq >> 1;
    const int mt  = wid;                            // 16-batch m-tile
    const int p0  = oh * OWD + ow0;

    // ---- B direct-load addressing: frag elem j of chunk kc, tile nt reads
    //      f = ((fq&1)*8+j)*9 + 2*kc + fqh, o = nt*16+fr, hi 2 bytes of f32.
    const int fbase = (fq & 1) * 72 + fqh;
    const char* wB  = (const char*)wgt + (size_t)p0 * WBYTES
                    + fbase * 128 + fr * 4 + 2;
    const int k4b = fqh ? 0 : 1024;    // kc=4: g=8 (real) / clamp (A is 0)

    short8 R0[10], R1[10];             // [kc*2+nt], position dbuf
    auto issueB = [&](int q, short8 (&R)[10]) {
        const char* wq  = wB + (size_t)q * WBYTES;
        const char* wq4 = wq + k4b;
        #pragma unroll
        for (int kc = 0; kc < 4; ++kc)
            #pragma unroll
            for (int nt = 0; nt < 2; ++nt)
                #pragma unroll
                for (int j = 0; j < 8; ++j)
                    R[kc * 2 + nt][j] = (short)*(const unsigned short*)
                        (wq + kc * 256 + nt * 64 + j * 1152);
        #pragma unroll
        for (int nt = 0; nt < 2; ++nt)
            #pragma unroll
            for (int j = 0; j < 8; ++j)
                R[8 + nt][j] = (short)*(const unsigned short*)
                    (wq4 + nt * 64 + j * 1152);
    };

    // prologue: two positions of B in flight before/during A staging
    issueB(0, R0);
    if (TW > 1) issueB(1, R1);

    // ---- stage A slab: Araw granule G = ((kh*AR_W+w)*64+b)*2 + gr, swizzled
    //      gr = half ^ ((b>>2)&1); G ^= (w&3)<<1. Truncating hi-ushort loads.
    for (int t = tid; t < 3 * WTOT * 64; t += 256) {
        int w   = t % WTOT;
        int rem = t / WTOT;
        int b   = rem & 63;
        int kh  = rem >> 6;
        const char* src = (const char*)(inp + (size_t)b * (CIN * HH * WW)
                        + (size_t)(oh + kh) * WW + (ow0 + w)) + 2;
        short8 h0, h1;
        #pragma unroll
        for (int c = 0; c < 8; ++c)
            h0[c] = (short)*(const unsigned short*)(src + c * (HH * WW * 4));
        #pragma unroll
        for (int c = 0; c < 8; ++c)
            h1[c] = (short)*(const unsigned short*)(src + (c + 8) * (HH * WW * 4));
        int s = (b >> 2) & 1;
        unsigned Gb = (unsigned)(((kh * AR_W + w) * 64 + b) * 2);
        unsigned wx = (unsigned)((w & 3) << 1);
        *(short8*)(Araw + (((Gb + s) ^ wx) << 3))       = h0;
        *(short8*)(Araw + (((Gb + (1 - s)) ^ wx) << 3)) = h1;
    }

    // ---- A-frag addressing (r4/r6-verified)
    const int b  = mt * 16 + fr;
    const int gr = (fq & 1) ^ ((b >> 2) & 1);
    unsigned abase_g[5]; int kwv[5];
    #pragma unroll
    for (int kc = 0; kc < 5; ++kc) {
        int g  = 2 * kc + fqh;
        int gc = (g > 8) ? 8 : g;
        int kh = (gc * 11) >> 5;
        int kw = gc - 3 * kh;
        abase_g[kc] = (unsigned)(((kh * AR_W + kw) * 64 + b) * 2 + gr);
        kwv[kc]     = kw;
    }

    __syncthreads();    // the only barrier; slab read-only afterwards

    f32x4 acc[TW][2];
    #pragma unroll
    for (int q = 0; q < TW; ++q) {
        acc[q][0] = (f32x4){0.f, 0.f, 0.f, 0.f};
        acc[q][1] = (f32x4){0.f, 0.f, 0.f, 0.f};
    }

    // ---- main loop, barrier-free: MFMA(q) on ring[q&1]; refill for q+2
    #pragma unroll
    for (int q = 0; q < TW; ++q) {
        short8 (&R)[10] = (q & 1) ? R1 : R0;
        #pragma unroll
        for (int kc = 0; kc < 5; ++kc) {
            short8 av;
            if (kc == 4 && fqh == 1) {
                av = (short8){0, 0, 0, 0, 0, 0, 0, 0};   // K in [144,160)
            } else {
                unsigned gi = (abase_g[kc] + (unsigned)(q * 128))
                            ^ (unsigned)(((q + kwv[kc]) & 3) << 1);
                av = *(const short8*)(Araw + (gi << 3));
            }
            acc[q][0] = __builtin_amdgcn_mfma_f32_16x16x32_bf16(
                            av, R[kc * 2 + 0], acc[q][0], 0, 0, 0);
            acc[q][1] = __builtin_amdgcn_mfma_f32_16x16x32_bf16(
                            av, R[kc * 2 + 1], acc[q][1], 0, 0, 0);
        }
        if (q + 2 < TW) issueB(q + 2, R);   // same parity buffer
    }

    // ---- epilogue: lane owns (b_out = mt*16+fq*4+r, o = nt*16+fr),
    //      TW consecutive floats along ow (8B-aligned f32x2 stores)
    #pragma unroll
    for (int r = 0; r < 4; ++r)
        #pragma unroll
        for (int nt = 0; nt < 2; ++nt) {
            float* dst = out
                + ((size_t)((mt * 16 + fq * 4 + r) * OUTC + nt * 16 + fr)) * POUT
                + (size_t)oh * OWD + ow0;
            #pragma unroll
            for (int j = 0; j < TW / 2; ++j) {
                f32x2 v = { acc[2 * j][nt][r], acc[2 * j + 1][nt][r] };
                *(f32x2*)(dst + 2 * j) = v;
            }
        }
}

__global__ __launch_bounds__(256, 3) void localconv_kernel(
    const float* __restrict__ inp,
    const float* __restrict__ wgt,
    float* __restrict__ out)
{
    __shared__ unsigned short Araw[AR_ELEMS];   // 48 KB -> 3 blocks/CU

    // bijective chunked XCD swizzle: 682 blocks -> XCD 0,1 get 86, rest 85;
    // within an XCD, l contiguous (same-row strips share the XCD's L2).
    const int bid = blockIdx.x;
    const int xcd = bid & 7, i = bid >> 3;
    const int l   = (xcd < 2) ? xcd * 86 + i : 172 + (xcd - 2) * 85 + i;
    const int oh    = l / 11;
    const int strip = l % 11;

    if (strip < 10) conv_body<6>(inp, wgt, out, oh, strip * 6, Araw);
    else            conv_body<2>(inp, wgt, out, oh, 60, Araw);
}

extern "C" void kernel_launch(void* const* d_in, const int* in_sizes, int n_in,
                              void* d_out, int out_size, void* d_ws, size_t ws_size,
                              hipStream_t stream) {
    const float* inp = (const float*)d_in[0];
    const float* wgt = (const float*)d_in[1];
    float* out = (float*)d_out;
    localconv_kernel<<<dim3(682), 256, 0, stream>>>(inp, wgt, out);
}

// Round 8
// 47.502 us; speedup vs baseline: 2.0556x; 2.0556x over previous
//
#include <hip/hip_runtime.h>

// LocalConv: out[b][o][oh][ow] = sum_f patch[p][b][f] * W[p][f][o]
// B=64, C=16, H=W=64, K=3x3, OH=OW=62, OUT_CH=32, FEAT=144, P=3844
// Round 8: r6 structure + counted-vmcnt barriers (no vmcnt(0) drain in the
// main loop), depth-4 weight ring, truncating bf16 loads (no f2bf VALU).
// K permuted: f'' = (kh*3+kw)*16 + c ; f = c*9 + g.
#define CIN    16
#define HH     64
#define WW     64
#define OHD    62
#define OWD    62
#define OUTC   32
#define FEATN  144
#define POUT   (OHD*OWD)
#define WBYTES (FEATN*OUTC*4)           // 18432 B / position
#define LSTRB  152                      // B row stride: 144 real + 8 zero pad
#define AR_W   8                        // A slab w-dim (max TW+2)
#define AR_ELEMS   (3*AR_W*64*16)       // 24576 elems = 49152 B
#define BBUF_ELEMS (OUTC*LSTRB + 8)     // 4872 (last 8 = zero guard)
#define SMEM_BYTES ((AR_ELEMS + 2*BBUF_ELEMS)*2)   // 68640 B

typedef __attribute__((ext_vector_type(8))) short  short8;
typedef __attribute__((ext_vector_type(4))) float  f32x4;
typedef __attribute__((ext_vector_type(2))) float  f32x2;

// barrier WITHOUT vmcnt(0) drain: LDS ops complete, global loads stay in flight
__device__ __forceinline__ void softBarrier() {
    asm volatile("s_waitcnt lgkmcnt(0)" ::: "memory");
    __builtin_amdgcn_sched_barrier(0);
    __builtin_amdgcn_s_barrier();
    __builtin_amdgcn_sched_barrier(0);
}

template<int TW>
__device__ __forceinline__ void conv_body(
    const float* __restrict__ inp, const float* __restrict__ wgt,
    float* __restrict__ out, int oh, int ow0,
    unsigned short* __restrict__ Araw, unsigned short* __restrict__ B_lds)
{
    const int tid = threadIdx.x;
    constexpr int WTOT = TW + 2;

    // ---- weight stream: thread = (o_w = tid&31, c_w = tid>>5 in 0..15).
    //      9 truncating ushort loads/thread/position (hi 2B of f32, f = c_w*9+g).
    //      Each wave-instr = 2 dense 128B lines. Depth-4 register ring.
    const int o_w = tid & 31;
    const int c_w = tid >> 5;
    const int p0  = oh * OWD + ow0;
    const char* wbase = (const char*)wgt + (size_t)p0 * WBYTES
                      + (size_t)(c_w * 288 + o_w) * 4 + 2;
    unsigned short ring[4][9];
    auto issue = [&](int t) {            // t compile-time under full unroll
        const char* p = wbase + (size_t)t * WBYTES;
        #pragma unroll
        for (int g = 0; g < 9; ++g)
            ring[t & 3][g] = *(const unsigned short*)(p + g * 128);
    };
    const int wb_base = o_w * LSTRB + c_w;     // + g*16
    auto writeB = [&](int t, unsigned short* Bb) {
        #pragma unroll
        for (int g = 0; g < 9; ++g)
            Bb[wb_base + g * 16] = ring[t & 3][g];
    };

    // ---- prologue loads first (independent of LDS staging below)
    issue(0);
    if (TW > 1) issue(1);
    if (TW > 2) issue(2);
    if (TW > 3) issue(3);

    // ---- stage A slab (truncating hi-ushort loads):
    //      granule G = ((kh*AR_W+w)*64+b)*2 + gr, gr = half ^ ((b>>2)&1),
    //      G ^= (w&3)<<1  (spreads write banks)
    for (int t = tid; t < 3 * WTOT * 64; t += 512) {
        int w   = t % WTOT;
        int rem = t / WTOT;
        int b   = rem & 63;
        int kh  = rem >> 6;
        const char* src = (const char*)(inp + (size_t)b * (CIN * HH * WW)
                        + (size_t)(oh + kh) * WW + (ow0 + w)) + 2;
        short8 h0, h1;
        #pragma unroll
        for (int c = 0; c < 8; ++c)
            h0[c] = (short)*(const unsigned short*)(src + c * (HH * WW * 4));
        #pragma unroll
        for (int c = 0; c < 8; ++c)
            h1[c] = (short)*(const unsigned short*)(src + (c + 8) * (HH * WW * 4));
        int s = (b >> 2) & 1;
        unsigned Gb = (unsigned)(((kh * AR_W + w) * 64 + b) * 2);
        unsigned wx = (unsigned)((w & 3) << 1);
        *(short8*)(Araw + (((Gb + s) ^ wx) << 3))       = h0;
        *(short8*)(Araw + (((Gb + (1 - s)) ^ wx) << 3)) = h1;
    }

    // ---- zero B pad [144,152) per row + 8-elem guard, both buffers
    for (int t = tid; t < 2 * 264; t += 512) {
        int buf = t / 264, r = t % 264;
        int e = (r < 256) ? ((r >> 3) * LSTRB + 144 + (r & 7))
                          : (OUTC * LSTRB + (r & 7));
        B_lds[buf * BBUF_ELEMS + e] = 0;
    }

    writeB(0, B_lds);          // buf0 <- q0 (counted vmcnt via reg dep)

    // ---- fragment addressing (r4/r6-verified)
    const int wid = tid >> 6, lane = tid & 63;
    const int fr = lane & 15, fq = lane >> 4, fqh = fq >> 1;
    const int mt = wid >> 1, nt = wid & 1;           // 4 m-tiles x 2 n-tiles
    const int b  = mt * 16 + fr;
    const int gr = (fq & 1) ^ ((b >> 2) & 1);
    unsigned abase_g[5]; int kwv[5]; int boff[5];
    #pragma unroll
    for (int kc = 0; kc < 5; ++kc) {
        int g  = 2 * kc + fqh;                 // 9 -> pad (zero A-frag)
        int gc = (g > 8) ? 8 : g;
        int kh = (gc * 11) >> 5;               // gc/3
        int kw = gc - 3 * kh;
        abase_g[kc] = (unsigned)(((kh * AR_W + kw) * 64 + b) * 2 + gr);
        kwv[kc]     = kw;
        boff[kc]    = (nt * 16 + fr) * LSTRB + kc * 32 + fq * 8;
    }

    softBarrier();   // A slab + B buf0 ready; ring 1..3 loads stay in flight

    f32x4 acc[TW];
    #pragma unroll
    for (int q = 0; q < TW; ++q) acc[q] = (f32x4){0.f, 0.f, 0.f, 0.f};

    // ---- main loop: MFMA(q) | issue(q+4) | writeB(q+1) | soft barrier
    #pragma unroll
    for (int q = 0; q < TW; ++q) {
        const unsigned short* Bc = B_lds + (q & 1) * BBUF_ELEMS;
        #pragma unroll
        for (int kc = 0; kc < 5; ++kc) {
            short8 a;
            if (kc == 4 && fqh == 1) {
                a = (short8){0, 0, 0, 0, 0, 0, 0, 0};   // K in [144,160): A=0
            } else {
                unsigned gi = (abase_g[kc] + (unsigned)(q * 128))
                              ^ (unsigned)(((q + kwv[kc]) & 3) << 1);
                a = *(const short8*)(Araw + (gi << 3));
            }
            short8 bfv = *(const short8*)(Bc + boff[kc]);
            acc[q] = __builtin_amdgcn_mfma_f32_16x16x32_bf16(a, bfv, acc[q], 0, 0, 0);
        }
        if (q + 4 < TW) issue(q + 4);
        if (q + 1 < TW) {
            writeB(q + 1, B_lds + ((q + 1) & 1) * BBUF_ELEMS);
            softBarrier();
        }
    }

    // ---- epilogue: lane owns (b_out = mt*16+fq*4+r, o = nt*16+fr),
    //      TW consecutive floats along ow (8B-aligned f32x2 stores)
    const int o = nt * 16 + fr;
    #pragma unroll
    for (int r = 0; r < 4; ++r) {
        float* dst = out + ((size_t)((mt * 16 + fq * 4 + r) * OUTC + o)) * POUT
                         + (size_t)oh * OWD + ow0;
        #pragma unroll
        for (int j = 0; j < TW / 2; ++j) {
            f32x2 v = { acc[2 * j][r], acc[2 * j + 1][r] };
            *(f32x2*)(dst + 2 * j) = v;
        }
    }
}

__global__ __launch_bounds__(512, 4) void localconv_kernel(
    const float* __restrict__ inp,
    const float* __restrict__ wgt,
    float* __restrict__ out)
{
    extern __shared__ unsigned short smem[];
    unsigned short* Araw  = smem;
    unsigned short* B_lds = smem + AR_ELEMS;

    // bijective chunked XCD swizzle: 682 blocks -> XCD 0,1 get 86, rest 85;
    // within an XCD, l contiguous (same-row strips share the XCD's L2).
    const int bid = blockIdx.x;
    const int xcd = bid & 7, i = bid >> 3;
    const int l   = (xcd < 2) ? xcd * 86 + i : 172 + (xcd - 2) * 85 + i;
    const int oh    = l / 11;
    const int strip = l % 11;

    if (strip < 10) conv_body<6>(inp, wgt, out, oh, strip * 6, Araw, B_lds);
    else            conv_body<2>(inp, wgt, out, oh, 60, Araw, B_lds);
}

extern "C" void kernel_launch(void* const* d_in, const int* in_sizes, int n_in,
                              void* d_out, int out_size, void* d_ws, size_t ws_size,
                              hipStream_t stream) {
    const float* inp = (const float*)d_in[0];
    const float* wgt = (const float*)d_in[1];
    float* out = (float*)d_out;
    hipFuncSetAttribute((const void*)localconv_kernel,
                        hipFuncAttributeMaxDynamicSharedMemorySize, SMEM_BYTES);
    localconv_kernel<<<dim3(682), 512, SMEM_BYTES, stream>>>(inp, wgt, out);
}